// Round 10
// baseline (62.139 us; speedup 1.0000x reference)
//
#include <hip/hip_runtime.h>

// GPLoss: gradient-profile loss, scalar output.
// Main pass: 3072 blocks x 256 thr; block = one 16-row band of one plane.
// Wave w: rowgrp (w>>1) -> rows [h0+8rg, +8), colhalf (w&1) -> 256 cols;
// lane owns 4 cols (float4 loads). Row stats: 6 DPP chains/row (VALU pipe).
// Col stats: per-thread regs -> 2-phase LDS merge -> colPart slot written
// NON-TEMPORALLY (37.8 MB bypasses L3 so the 201 MB inputs stay resident
// across timed replays -- the round-7 regression cause).
// ws: colPart f32[96*32][6][512] ; rowPart f32[3072][2] ; dblk f64[192]

typedef float f32x4 __attribute__((ext_vector_type(4)));  // nt-builtin-legal

#define DPP_ADD(x, ctrl, rmask) \
  x += __int_as_float(__builtin_amdgcn_update_dpp(0, __float_as_int(x), ctrl, rmask, 0xf, false))

__device__ __forceinline__ float wave_dpp_sum(float x){
  DPP_ADD(x, 0x111, 0xf);   // row_shr:1
  DPP_ADD(x, 0x112, 0xf);   // row_shr:2
  DPP_ADD(x, 0x114, 0xf);   // row_shr:4
  DPP_ADD(x, 0x118, 0xf);   // row_shr:8
  DPP_ADD(x, 0x142, 0xa);   // row_bcast:15 -> rows 1,3
  DPP_ADD(x, 0x143, 0xc);   // row_bcast:31 -> rows 2,3
  return x;                 // lane 63 holds the 64-lane sum
}

__device__ __forceinline__ float cos_sim(float d, float sx, float sr){
  float nx = fmaxf(sqrtf(sx), 1e-12f);
  float nr = fmaxf(sqrtf(sr), 1e-12f);
  return d / (nx * nr);
}

__global__ __launch_bounds__(256) void gp_uni(
    const float* __restrict__ X, const float* __restrict__ R,
    float* __restrict__ rowPart, float* __restrict__ colPart)
{
  const int bid = blockIdx.x;
  const int p = bid >> 5, q = bid & 31;        // plane, 16-row band
  const int tid = threadIdx.x, w = tid >> 6, l = tid & 63;
  const int rg = w >> 1;                        // row-group: rows [h0+8rg,+8)
  const int wp = w & 1;                         // col half: wp*256
  const size_t plane = (size_t)p * (512u * 512u);
  const float* xp = X + plane;
  const float* rp = R + plane;
  const int c  = wp*256 + 4*l;                  // cols c..c+3
  const int cn = (c+4 < 512) ? c+4 : 511;       // f_v halo col (clamped)
  const bool tlast = (c == 508);                // col 511: no f_v
  const int h0 = q*16 + rg*8;                   // first row of this wave

  __shared__ float colbuf[6][512];              // 12 KB band merge
  __shared__ float rowbuf[16][2][6];            // 768 B row stats

  float cv0[4], cv1[4], cv2[4], ch0[4], ch1[4], ch2[4];
  #pragma unroll
  for (int j = 0; j < 4; ++j){
    cv0[j]=0.f; cv1[j]=0.f; cv2[j]=0.f;
    ch0[j]=0.f; ch1[j]=0.f; ch2[j]=0.f;
  }

  const float* xr0 = xp + (size_t)h0*512;
  const float* rr0 = rp + (size_t)h0*512;
  float4 xc4 = *(const float4*)(xr0 + c);
  float4 rc4 = *(const float4*)(rr0 + c);
  float  xhv = xr0[cn], rhv = rr0[cn];

  #pragma unroll 2
  for (int k = 0; k < 8; ++k){
    const int h  = h0 + k;
    const int hn = (h+1 < 512) ? h+1 : 511;     // h==511: next==cur -> dh=0
    const float* xr = xp + (size_t)hn*512;
    const float* rr = rp + (size_t)hn*512;
    const float4 nx4 = *(const float4*)(xr + c);
    const float4 nr4 = *(const float4*)(rr + c);
    const float  nxh = xr[cn], nrh = rr[cn];

    const float ax[4] = {xc4.x, xc4.y, xc4.z, xc4.w};
    const float ar[4] = {rc4.x, rc4.y, rc4.z, rc4.w};
    const float bx[4] = {nx4.x, nx4.y, nx4.z, nx4.w};
    const float br[4] = {nr4.x, nr4.y, nr4.z, nr4.w};

    float dv[4], ev[4];
    dv[0]=ax[0]-ax[1]; dv[1]=ax[1]-ax[2]; dv[2]=ax[2]-ax[3];
    ev[0]=ar[0]-ar[1]; ev[1]=ar[1]-ar[2]; ev[2]=ar[2]-ar[3];
    dv[3] = tlast ? 0.f : (ax[3]-xhv);
    ev[3] = tlast ? 0.f : (ar[3]-rhv);

    float p0=0.f,p1=0.f,p2=0.f, q0=0.f,q1=0.f,q2=0.f;
    #pragma unroll
    for (int j = 0; j < 4; ++j){
      p0 = fmaf(dv[j],ev[j],p0); p1 = fmaf(dv[j],dv[j],p1); p2 = fmaf(ev[j],ev[j],p2);
      cv0[j] = fmaf(dv[j],ev[j],cv0[j]);
      cv1[j] = fmaf(dv[j],dv[j],cv1[j]);
      cv2[j] = fmaf(ev[j],ev[j],cv2[j]);
      const float dh = ax[j]-bx[j];
      const float eh = ar[j]-br[j];
      q0 = fmaf(dh,eh,q0); q1 = fmaf(dh,dh,q1); q2 = fmaf(eh,eh,q2);
      ch0[j] = fmaf(dh,eh,ch0[j]);
      ch1[j] = fmaf(dh,dh,ch1[j]);
      ch2[j] = fmaf(eh,eh,ch2[j]);
    }

    // 6 independent DPP chains (VALU pipe)
    p0 = wave_dpp_sum(p0); p1 = wave_dpp_sum(p1); p2 = wave_dpp_sum(p2);
    q0 = wave_dpp_sum(q0); q1 = wave_dpp_sum(q1); q2 = wave_dpp_sum(q2);
    if (l == 63){
      const int rr_ = rg*8 + k;
      rowbuf[rr_][wp][0]=p0; rowbuf[rr_][wp][1]=p1; rowbuf[rr_][wp][2]=p2;
      rowbuf[rr_][wp][3]=q0; rowbuf[rr_][wp][4]=q1; rowbuf[rr_][wp][5]=q2;
    }

    xc4 = nx4; rc4 = nr4; xhv = nxh; rhv = nrh;
  }

  // ---- col stats: rowgrp 0 writes, rowgrp 1 accumulates, then nt-stream out
  if (rg == 0){
    *(float4*)&colbuf[0][c] = make_float4(cv0[0],cv0[1],cv0[2],cv0[3]);
    *(float4*)&colbuf[1][c] = make_float4(cv1[0],cv1[1],cv1[2],cv1[3]);
    *(float4*)&colbuf[2][c] = make_float4(cv2[0],cv2[1],cv2[2],cv2[3]);
    *(float4*)&colbuf[3][c] = make_float4(ch0[0],ch0[1],ch0[2],ch0[3]);
    *(float4*)&colbuf[4][c] = make_float4(ch1[0],ch1[1],ch1[2],ch1[3]);
    *(float4*)&colbuf[5][c] = make_float4(ch2[0],ch2[1],ch2[2],ch2[3]);
  }
  __syncthreads();
  if (rg == 1){
    float4 t;
    t = *(float4*)&colbuf[0][c]; t.x+=cv0[0]; t.y+=cv0[1]; t.z+=cv0[2]; t.w+=cv0[3]; *(float4*)&colbuf[0][c]=t;
    t = *(float4*)&colbuf[1][c]; t.x+=cv1[0]; t.y+=cv1[1]; t.z+=cv1[2]; t.w+=cv1[3]; *(float4*)&colbuf[1][c]=t;
    t = *(float4*)&colbuf[2][c]; t.x+=cv2[0]; t.y+=cv2[1]; t.z+=cv2[2]; t.w+=cv2[3]; *(float4*)&colbuf[2][c]=t;
    t = *(float4*)&colbuf[3][c]; t.x+=ch0[0]; t.y+=ch0[1]; t.z+=ch0[2]; t.w+=ch0[3]; *(float4*)&colbuf[3][c]=t;
    t = *(float4*)&colbuf[4][c]; t.x+=ch1[0]; t.y+=ch1[1]; t.z+=ch1[2]; t.w+=ch1[3]; *(float4*)&colbuf[4][c]=t;
    t = *(float4*)&colbuf[5][c]; t.x+=ch2[0]; t.y+=ch2[1]; t.z+=ch2[2]; t.w+=ch2[3]; *(float4*)&colbuf[5][c]=t;
  }
  __syncthreads();
  f32x4* slot = (f32x4*)(colPart + (size_t)bid * (6*512));
  const f32x4* cb = (const f32x4*)colbuf;
  #pragma unroll
  for (int i = 0; i < 3; ++i)
    __builtin_nontemporal_store(cb[tid + 256*i], &slot[tid + 256*i]);

  // ---- row finalize: combine col-half pairs, cos, block sum (wave 0)
  if (tid < 64){
    float rv = 0.f, rh = 0.f;
    if (tid < 16){
      const float a0 = rowbuf[tid][0][0] + rowbuf[tid][1][0];
      const float a1 = rowbuf[tid][0][1] + rowbuf[tid][1][1];
      const float a2 = rowbuf[tid][0][2] + rowbuf[tid][1][2];
      const float b0 = rowbuf[tid][0][3] + rowbuf[tid][1][3];
      const float b1 = rowbuf[tid][0][4] + rowbuf[tid][1][4];
      const float b2 = rowbuf[tid][0][5] + rowbuf[tid][1][5];
      rv = cos_sim(a0,a1,a2);
      const int h = q*16 + tid;
      rh = (h < 511) ? cos_sim(b0,b1,b2) : 0.f;
    }
    rv = wave_dpp_sum(rv);
    rh = wave_dpp_sum(rh);
    if (tid == 63){
      rowPart[2*bid+0] = rv;
      rowPart[2*bid+1] = rh;
    }
  }
}

// ---------------- finish: reduce col partials over 32 slots ------------------
__global__ __launch_bounds__(256) void gp_cols(
    const float* __restrict__ colPart, double* __restrict__ dblk)
{
  const int p = blockIdx.x >> 1;
  const int f = blockIdx.x & 1;    // 0 = fv, 1 = fh
  const int tid = threadIdx.x;
  double acc = 0.0;
  for (int c = tid; c < 512; c += 256){
    float d = 0.f, a = 0.f, b = 0.f;
    #pragma unroll 4
    for (int s = 0; s < 32; ++s){
      const float* sp = colPart + ((size_t)(p*32 + s) * 6 + f*3) * 512;
      d += __builtin_nontemporal_load(sp + c);
      a += __builtin_nontemporal_load(sp + 512 + c);
      b += __builtin_nontemporal_load(sp + 1024 + c);
    }
    acc += (double)cos_sim(d, a, b);   // fv col 511: cos(0,0,0)=0, harmless
  }
  #pragma unroll
  for (int m = 1; m < 64; m <<= 1) acc += __shfl_xor(acc, m, 64);
  __shared__ double ls[4];
  const int w = tid >> 6, l = tid & 63;
  if (l == 0) ls[w] = acc;
  __syncthreads();
  if (tid == 0) dblk[blockIdx.x] = ls[0] + ls[1] + ls[2] + ls[3];
}

__global__ __launch_bounds__(256) void gp_fin(
    const double* __restrict__ dblk, const float* __restrict__ rowPart,
    int nblk, float* __restrict__ out)
{
  const int tid = threadIdx.x;
  double rv = 0, rh = 0, cv = 0, ch = 0;
  for (int i = tid; i < nblk; i += 256){
    rv += (double)rowPart[2*i];
    rh += (double)rowPart[2*i+1];
  }
  for (int i = tid; i < 192; i += 256){
    if (i & 1) ch += dblk[i]; else cv += dblk[i];
  }
  #pragma unroll
  for (int m = 1; m < 64; m <<= 1){
    rv += __shfl_xor(rv, m, 64); rh += __shfl_xor(rh, m, 64);
    cv += __shfl_xor(cv, m, 64); ch += __shfl_xor(ch, m, 64);
  }
  __shared__ double ls[4][4];
  const int w = tid >> 6, l = tid & 63;
  if (l == 0){ ls[w][0]=rv; ls[w][1]=rh; ls[w][2]=cv; ls[w][3]=ch; }
  __syncthreads();
  if (tid == 0){
    double RV=0, RH=0, CV=0, CH=0;
    #pragma unroll
    for (int i = 0; i < 4; ++i){ RV+=ls[i][0]; RH+=ls[i][1]; CV+=ls[i][2]; CH+=ls[i][3]; }
    const double t = RV/512.0 + RH/511.0 + CV/511.0 + CH/512.0;
    out[0] = (float)(-t / 32.0);
  }
}

extern "C" void kernel_launch(void* const* d_in, const int* in_sizes, int n_in,
                              void* d_out, int out_size, void* d_ws, size_t ws_size,
                              hipStream_t stream) {
  const float* X = (const float*)d_in[0];
  const float* R = (const float*)d_in[1];
  float* out = (float*)d_out;

  float*  colPart = (float*)d_ws;                         // 96*32*6*512 f32
  float*  rowPart = colPart + (size_t)96*32*6*512;        // 3072*2 f32
  double* dblk    = (double*)(rowPart + (size_t)3072*2);  // 192 f64

  gp_uni <<<dim3(3072), dim3(256), 0, stream>>>(X, R, rowPart, colPart);
  gp_cols<<<dim3(192),  dim3(256), 0, stream>>>(colPart, dblk);
  gp_fin <<<dim3(1),    dim3(256), 0, stream>>>(dblk, rowPart, 3072, out);
}